// Round 5
// baseline (251.282 us; speedup 1.0000x reference)
//
#include <hip/hip_runtime.h>
#include <stdint.h>

#define NROWS 8192
#define DIM   2048
#define MARGIN 2.0f

// ---- 256x256 8-phase tile kernel geometry ----
#define BT2     256
#define BK2     64
#define NKT     (DIM / BK2)              // 32 K-tiles
#define NT2     (NROWS / BT2)            // 32 tile-rows
#define NTILES2 (NT2 * (NT2 + 1) / 2)    // 528 upper-tri tiles
#define NOVER   16                       // overhang tiles = logical bids 0..15
#define ABUF_EL 16384                    // 256*64 elements (A region per buffer)
#define BUF_EL  32768                    // A + B regions per buffer
#define HALF_EL 8192                     // 128*64 elements per half-tile

typedef __attribute__((ext_vector_type(8))) short short8;   // 8 bf16
typedef __attribute__((ext_vector_type(4))) float floatx4;  // C/D frag

__device__ __forceinline__ ushort f2bf(float x) {
    uint32_t u = __float_as_uint(x);
    uint32_t r = u + 0x7fffu + ((u >> 16) & 1u);   // RNE
    return (ushort)(r >> 16);
}
__device__ __forceinline__ float bf2f(ushort b) {
    return __uint_as_float(((uint32_t)b) << 16);
}

// triangular decode (ti <= tj): off(r) = r*NT2 - r(r-1)/2
__device__ __forceinline__ void decode_tile(int bid, int* ti, int* tj) {
    float fn = (float)NT2 + 0.5f;
    int r = (int)(fn - sqrtf(fn * fn - 2.0f * (float)bid));
    if (r < 0) r = 0;
    if (r >= NT2) r = NT2 - 1;
    while ((r + 1) * NT2 - ((r + 1) * r) / 2 <= bid) ++r;
    while (r * NT2 - (r * (r - 1)) / 2 > bid) --r;
    *ti = r;
    *tj = r + (bid - (r * NT2 - (r * (r - 1)) / 2));
}

// ---------------- kernel 1: fp32 -> bf16 cast + row sum of squares ----------
__global__ __launch_bounds__(256) void prep_kernel(const float* __restrict__ p,
                                                   ushort* __restrict__ pb,
                                                   float* __restrict__ sq) {
    int row = blockIdx.x;
    int t = threadIdx.x;
    const float4* prow = (const float4*)(p + (size_t)row * DIM);
    ushort* brow = pb + (size_t)row * DIM;
    float s = 0.f;
#pragma unroll
    for (int h = 0; h < 2; ++h) {
        int idx = h * 256 + t;
        float4 v = prow[idx];
        ushort4 o;
        o.x = f2bf(v.x); o.y = f2bf(v.y); o.z = f2bf(v.z); o.w = f2bf(v.w);
        float a = bf2f(o.x), b = bf2f(o.y), c = bf2f(o.z), d = bf2f(o.w);
        s += a * a + b * b + c * c + d * d;   // sumsq of ROUNDED values
        *(ushort4*)(brow + idx * 4) = o;
    }
#pragma unroll
    for (int o = 32; o > 0; o >>= 1) s += __shfl_down(s, o, 64);
    __shared__ float wsums[4];
    int lane = t & 63, wvv = t >> 6;
    if (lane == 0) wsums[wvv] = s;
    __syncthreads();
    if (t == 0) sq[row] = wsums[0] + wsums[1] + wsums[2] + wsums[3];
}

// ---------------- half-tile stage: global -> LDS (linear dest, pre-swizzled src)
// which: 0 = A half0, 1 = A half1, 2 = B half0, 3 = B half1, for K-tile t.
// t >= kend clamps to t-2: same buffer/region (parity preserved), data dead;
// the write window for the phase placement is identical, so still race-free.
__device__ __forceinline__ void stage_ht(const ushort* __restrict__ pb,
                                         ushort* lds, int t, int which,
                                         int ibase, int jbase, int tid, int kend) {
    if (t >= kend) t -= 2;
    const int h = which & 1;
    const int row0 = ((which >= 2) ? jbase : ibase) + h * 128;
    const ushort* g0 = pb + (size_t)row0 * DIM + t * BK2;
    ushort* l0 = lds + (t & 1) * BUF_EL + ((which >= 2) ? ABUF_EL : 0) + h * HALF_EL;
#pragma unroll
    for (int r = 0; r < 2; ++r) {
        int row = r * 64 + (tid >> 3);                 // row within half-tile
        int c8 = (tid & 7) ^ ((tid >> 3) & 7);         // pre-swizzled col slot
        const ushort* g = g0 + (size_t)row * DIM + c8 * 8;
        ushort* l = l0 + r * 4096 + (tid >> 6) * 512;  // wave-uniform base (+lane*16B HW)
        __builtin_amdgcn_global_load_lds(
            (const __attribute__((address_space(1))) uint32_t*)g,
            (__attribute__((address_space(3))) uint32_t*)l, 16, 0, 0);
    }
}

#define BARF()   do { __builtin_amdgcn_s_barrier(); \
                      asm volatile("" ::: "memory"); } while (0)
#define WAITL()  asm volatile("s_waitcnt lgkmcnt(0)" ::: "memory")
#define WAITV8() asm volatile("s_waitcnt vmcnt(8)" ::: "memory")
#define WAITV0() asm volatile("s_waitcnt vmcnt(0)" ::: "memory")
#define PRIO1()  __builtin_amdgcn_s_setprio(1)
#define PRIO0()  __builtin_amdgcn_s_setprio(0)

// swizzled ds_read of 16B fragments: row-major [*][64], col8 ^= (row&7) = (lane&7)
#define READ_A(AB, MH)                                                         \
    _Pragma("unroll") for (int m = 0; m < 4; ++m)                              \
    _Pragma("unroll") for (int k = 0; k < 2; ++k)                              \
        afr[m][k] = *(const short8*)&(AB)[                                     \
            (wr * 128 + ((MH) * 4 + m) * 16 + (lane & 15)) * 64 +              \
            (((k * 4 + (lane >> 4)) ^ (lane & 7)) * 8)];

#define READ_B(BB, NH)                                                         \
    _Pragma("unroll") for (int n = 0; n < 2; ++n)                              \
    _Pragma("unroll") for (int k = 0; k < 2; ++k)                              \
        bfr[(NH) * 2 + n][k] = *(const short8*)&(BB)[                          \
            (wc * 64 + ((NH) * 2 + n) * 16 + (lane & 15)) * 64 +               \
            (((k * 4 + (lane >> 4)) ^ (lane & 7)) * 8)];

#define MFMA_Q(MH, NH)                                                         \
    _Pragma("unroll") for (int m = 0; m < 4; ++m)                              \
    _Pragma("unroll") for (int n = 0; n < 2; ++n)                              \
    _Pragma("unroll") for (int k = 0; k < 2; ++k)                              \
        acc[(MH) * 4 + m][(NH) * 2 + n] =                                      \
            __builtin_amdgcn_mfma_f32_16x16x32_bf16(                           \
                afr[m][k], bfr[(NH) * 2 + n][k],                               \
                acc[(MH) * 4 + m][(NH) * 2 + n], 0, 0, 0);

// One K-tile = 4 phases. All stages for tile T+2 issue in P3/P4:
//   P3: B0,B1(T+2)->buf (safe: ALL B reads of buf close at end-P2 barrier)
//   P4: A0,A1(T+2)->buf (safe: ALL A reads of buf close at end-P3 barrier)
// Boundary s_waitcnt vmcnt(8): tile T+1's 8 loads retired (in-order count),
// tile T+2's 8 stay in flight. Never vmcnt(0) in-loop.
#define TILE_STEP(T, BUF)                                                      \
    {                                                                          \
        const ushort* Ab = &lds[(BUF) * BUF_EL];                               \
        const ushort* Bb = &lds[(BUF) * BUF_EL + ABUF_EL];                     \
        /* P1: Q(0,0) — 12 ds_reads, no stage */                               \
        READ_A(Ab, 0);                                                         \
        READ_B(Bb, 0);                                                         \
        BARF(); WAITL();                                                       \
        PRIO1(); MFMA_Q(0, 0); PRIO0();                                        \
        BARF();                                                                \
        /* P2: Q(0,1) — 4 ds_reads */                                          \
        READ_B(Bb, 1);                                                         \
        BARF(); WAITL();                                                       \
        PRIO1(); MFMA_Q(0, 1); PRIO0();                                        \
        BARF();                                                                \
        /* P3: Q(1,0) — 8 ds_reads + stage B(T+2) */                           \
        READ_A(Ab, 1);                                                         \
        stage_ht(pb, lds, (T) + 2, 2, ibase, jbase, tid, kend);                \
        stage_ht(pb, lds, (T) + 2, 3, ibase, jbase, tid, kend);                \
        BARF(); WAITL();                                                       \
        PRIO1(); MFMA_Q(1, 0); PRIO0();                                        \
        BARF();                                                                \
        /* P4: Q(1,1) — stage A(T+2), counted vmcnt at tile boundary */        \
        stage_ht(pb, lds, (T) + 2, 0, ibase, jbase, tid, kend);                \
        stage_ht(pb, lds, (T) + 2, 1, ibase, jbase, tid, kend);                \
        PRIO1(); MFMA_Q(1, 1); PRIO0();                                        \
        WAITV8();                                                              \
        BARF();                                                                \
    }

// ---------------- kernel 2: 256² 8-phase triangular Gram + fused loss -------
// Grid (nch>0) = 16*nch chunk blocks (dispatched FIRST) + 512 full tiles.
// Overhang = logical tiles 0..15, each split into nch K-chunks; chunks store
// f32 partial Gram; the LAST chunk per tile (atomic counter) reduces + loss.
// Grid (nch==0 fallback) = 528 full tiles (round-3 behavior).
__global__ __launch_bounds__(512) void tile2_kernel(
    const ushort* __restrict__ pb, const float* __restrict__ sq,
    const int* __restrict__ gt, double* __restrict__ accum,
    int* __restrict__ counters, float* __restrict__ partials,
    int nch, int lognch) {

    __shared__ ushort lds[2 * BUF_EL];   // 128 KiB: 2 x (A[256][64] + B[256][64])
    __shared__ float wsum[8];
    __shared__ int lastFlag;

    const int bx = (int)blockIdx.x;
    const int nchunkblk = nch << 4;      // 16*nch
    int bid, kbeg, kend, k_tile = 0;
    bool is_chunk = (bx < nchunkblk);
    if (is_chunk) {
        k_tile = bx >> lognch;
        int cidx = bx & (nch - 1);
        bid = k_tile;                    // overhang bids 0..15 (row ti=0; bid0 diag)
        int span = NKT >> lognch;
        kbeg = cidx * span; kend = kbeg + span;
    } else {
        int f = bx - nchunkblk;
        if (nch) bid = NOVER + ((f & 7) << 6) + (f >> 3);   // 512 = 8*64 bijective
        else     bid = (f & 7) * 66 + (f >> 3);             // 528 = 8*66 bijective
        kbeg = 0; kend = NKT;
    }

    int ti, tj;
    decode_tile(bid, &ti, &tj);

    const int tid = threadIdx.x;
    const int lane = tid & 63;
    const int wv = tid >> 6;
    const int wr = wv >> 2;   // 0..1 : wave row (128 rows each)
    const int wc = wv & 3;    // 0..3 : wave col (64 cols each)
    const int ibase = ti * BT2;
    const int jbase = tj * BT2;

    floatx4 acc[8][4] = {};
    short8 afr[4][2];
    short8 bfr[4][2];

    // prologue: tiles kbeg, kbeg+1 fully staged-issued; vmcnt(8) -> tile kbeg
    // resident, tile kbeg+1's 8 loads in flight (steady-state invariant).
    stage_ht(pb, lds, kbeg, 2, ibase, jbase, tid, kend);
    stage_ht(pb, lds, kbeg, 3, ibase, jbase, tid, kend);
    stage_ht(pb, lds, kbeg, 0, ibase, jbase, tid, kend);
    stage_ht(pb, lds, kbeg, 1, ibase, jbase, tid, kend);
    stage_ht(pb, lds, kbeg + 1, 2, ibase, jbase, tid, kend);
    stage_ht(pb, lds, kbeg + 1, 3, ibase, jbase, tid, kend);
    stage_ht(pb, lds, kbeg + 1, 0, ibase, jbase, tid, kend);
    stage_ht(pb, lds, kbeg + 1, 1, ibase, jbase, tid, kend);
    WAITV8();
    BARF();

    for (int s0 = kbeg; s0 < kend; s0 += 2) {   // kbeg even, span even
        TILE_STEP(s0, (s0 & 1));
        TILE_STEP(s0 + 1, ((s0 + 1) & 1));
    }
    WAITV0();   // drain dead tail stages before exit
    BARF();

    const float invd = 1.0f / (float)DIM;

    if (!is_chunk) {
        // fused epilogue: d2 -> contrastive term -> weighted partial sum
        float lsum = 0.f;
        int j0 = jbase + wc * 64 + (lane & 15);
        float sqj[4]; int gj[4];
#pragma unroll
        for (int n = 0; n < 4; ++n) { int j = j0 + n * 16; sqj[n] = sq[j]; gj[n] = gt[j]; }
        const float wb = (ti != tj) ? 2.0f : 1.0f;
#pragma unroll
        for (int mi = 0; mi < 8; ++mi) {
#pragma unroll
            for (int rr = 0; rr < 4; ++rr) {
                int i = ibase + wr * 128 + mi * 16 + (lane >> 4) * 4 + rr;
                float sqi = sq[i];
                int gi = gt[i];
#pragma unroll
                for (int n = 0; n < 4; ++n) {
                    int j = j0 + n * 16;
                    float d2 = fmaxf(sqi + sqj[n] - 2.0f * acc[mi][n][rr], 0.0f) * invd;
                    float term = (gi == gj[n]) ? d2 : fmaxf(MARGIN - d2, 0.0f);
                    float w = wb;
                    if (ti == tj && i == j) w = 2.0f;   // triu diagonal counted once*2
                    lsum += w * term;
                }
            }
        }
#pragma unroll
        for (int o = 32; o > 0; o >>= 1) lsum += __shfl_down(lsum, o, 64);
        if (lane == 0) wsum[wv] = lsum;
        __syncthreads();
        if (tid == 0) {
            float s = 0.f;
#pragma unroll
            for (int w = 0; w < 8; ++w) s += wsum[w];
            atomicAdd(accum, (double)s);
        }
        return;
    }

    // ---- chunk path: store partial Gram tile, column-major [j][i] ----
    {
        float* base = partials + ((size_t)(bx) << 16);   // slot = bx (chunk idx)
        int i0 = wr * 128 + (lane >> 4) * 4;
        int jl0 = wc * 64 + (lane & 15);
#pragma unroll
        for (int mi = 0; mi < 8; ++mi)
#pragma unroll
            for (int n = 0; n < 4; ++n)
                *(floatx4*)&base[(size_t)(jl0 + n * 16) * BT2 + i0 + mi * 16] = acc[mi][n];
    }
    __threadfence();        // agent release: flush partial stores toward LLC
    __syncthreads();
    if (tid == 0) {
        int old = atomicAdd(&counters[k_tile], 1);
        lastFlag = (old == nch - 1);
    }
    __syncthreads();
    if (!lastFlag) return;

    // ---- last chunk: reduce nch partials + loss for this overhang tile ----
    __threadfence();        // agent acquire: invalidate stale L2 before reads
    float lsum = 0.f;
    const float* pbase = partials + ((size_t)(k_tile * nch) << 16);
    for (int e4 = tid; e4 < 16384; e4 += 512) {
        float d0 = 0.f, d1 = 0.f, d2a = 0.f, d3 = 0.f;
        for (int c = 0; c < nch; ++c) {
            floatx4 v = *(const floatx4*)&pbase[((size_t)c << 16) + (e4 << 2)];
            d0 += v[0]; d1 += v[1]; d2a += v[2]; d3 += v[3];
        }
        int e = e4 << 2;
        int jl = e >> 8, il0 = e & 255;
        int j = jbase + jl;
        float sqjv = sq[j]; int gjv = gt[j];
        float dots[4] = {d0, d1, d2a, d3};
#pragma unroll
        for (int q = 0; q < 4; ++q) {
            int i = ibase + il0 + q;
            float dd = fmaxf(sq[i] + sqjv - 2.0f * dots[q], 0.0f) * invd;
            float term = (gt[i] == gjv) ? dd : fmaxf(MARGIN - dd, 0.0f);
            float w = (ti != tj) ? 2.0f : ((i == j) ? 2.0f : 1.0f);
            lsum += w * term;
        }
    }
#pragma unroll
    for (int o = 32; o > 0; o >>= 1) lsum += __shfl_down(lsum, o, 64);
    if (lane == 0) wsum[wv] = lsum;
    __syncthreads();
    if (tid == 0) {
        float s = 0.f;
#pragma unroll
        for (int w = 0; w < 8; ++w) s += wsum[w];
        atomicAdd(accum, (double)s);
    }
}

// ---------------- kernel 3: finalize ----------------------------------------
__global__ void finalize_kernel(const double* __restrict__ accum,
                                float* __restrict__ out) {
    if (threadIdx.x == 0)
        out[0] = (float)(accum[0] * (1.0 / ((double)NROWS * (double)(NROWS - 1))));
}

extern "C" void kernel_launch(void* const* d_in, const int* in_sizes, int n_in,
                              void* d_out, int out_size, void* d_ws, size_t ws_size,
                              hipStream_t stream) {
    (void)in_sizes; (void)n_in; (void)out_size;
    const float* p = (const float*)d_in[0];
    const int* gt = (const int*)d_in[1];
    float* out = (float*)d_out;

    // ws layout: pb 32MB | sq 32KB | accum 8B + counters 64B (256B slot) | partials
    ushort* pb = (ushort*)d_ws;
    size_t off = (size_t)NROWS * DIM * 2;               // 33,554,432
    float* sq = (float*)((char*)d_ws + off);
    off += (size_t)NROWS * sizeof(float);               // +32 KB
    double* accum = (double*)((char*)d_ws + off);
    int* counters = (int*)((char*)d_ws + off + 8);
    size_t ctrl_off = off;
    off += 256;
    float* partials = (float*)((char*)d_ws + off);

    const size_t partial_bytes_8 = (size_t)NOVER * 8 * BT2 * BT2 * 4;  // 32 MB
    const size_t partial_bytes_4 = (size_t)NOVER * 4 * BT2 * BT2 * 4;  // 16 MB
    int nch, lognch;
    if (ws_size >= off + partial_bytes_8)      { nch = 8; lognch = 3; }
    else if (ws_size >= off + partial_bytes_4) { nch = 4; lognch = 2; }
    else                                       { nch = 0; lognch = 0; }

    int grid = nch ? (16 * nch + 512) : NTILES2;

    (void)hipMemsetAsync((char*)d_ws + ctrl_off, 0, 256, stream);
    prep_kernel<<<NROWS, 256, 0, stream>>>(p, pb, sq);
    tile2_kernel<<<grid, 512, 0, stream>>>(pb, sq, gt, accum, counters,
                                           partials, nch, lognch);
    finalize_kernel<<<1, 64, 0, stream>>>(accum, out);
}

// Round 6
// 129.894 us; speedup vs baseline: 1.9345x; 1.9345x over previous
//
#include <hip/hip_runtime.h>
#include <stdint.h>

#define NROWS 8192
#define DIM   2048
#define MARGIN 2.0f
#define SCALEQ (127.0f / 6.0f)          // quantize scale
#define S2     ((6.0f / 127.0f) * (6.0f / 127.0f))   // dequant^2

// ---- 256x256 i8 8-phase tile kernel geometry (byte units) ----
#define BT2     256
#define BKB     128                      // K-bytes (=elems) per tile-step
#define NKT     (DIM / BKB)              // 16 K-tiles
#define NT2     (NROWS / BT2)            // 32 tile-rows
#define NTILES2 (NT2 * (NT2 + 1) / 2)    // 528 upper-tri tiles
#define ABUF_B  32768                    // A region bytes per buffer (256x128)
#define BUF_B   65536                    // A + B regions per buffer
#define HALF_B  16384                    // 128x128 half-tile bytes

typedef __attribute__((ext_vector_type(4)))  int  int4v;    // 4 VGPR operand
typedef __attribute__((ext_vector_type(16))) int  int16v;   // 32x32 i32 acc
typedef unsigned char uchar;

// triangular decode (ti <= tj): off(r) = r*NT2 - r(r-1)/2
__device__ __forceinline__ void decode_tile(int bid, int* ti, int* tj) {
    float fn = (float)NT2 + 0.5f;
    int r = (int)(fn - sqrtf(fn * fn - 2.0f * (float)bid));
    if (r < 0) r = 0;
    if (r >= NT2) r = NT2 - 1;
    while ((r + 1) * NT2 - ((r + 1) * r) / 2 <= bid) ++r;
    while (r * NT2 - (r * (r - 1)) / 2 > bid) --r;
    *ti = r;
    *tj = r + (bid - (r * NT2 - (r * (r - 1)) / 2));
}

__device__ __forceinline__ uint pack4(float4 v) {
    int q0 = (int)__builtin_rintf(v.x * SCALEQ);
    int q1 = (int)__builtin_rintf(v.y * SCALEQ);
    int q2 = (int)__builtin_rintf(v.z * SCALEQ);
    int q3 = (int)__builtin_rintf(v.w * SCALEQ);
    q0 = min(max(q0, -127), 127); q1 = min(max(q1, -127), 127);
    q2 = min(max(q2, -127), 127); q3 = min(max(q3, -127), 127);
    return (uint)(q0 & 0xFF) | ((uint)(q1 & 0xFF) << 8) |
           ((uint)(q2 & 0xFF) << 16) | ((uint)(q3 & 0xFF) << 24);
}

// ---------------- kernel 1: fp32 -> i8 quantize + fp32 row sum of squares ---
// sq from the fp32 ORIGINALS: cancels the quantization distance-inflation bias.
__global__ __launch_bounds__(256) void prep_kernel(const float* __restrict__ p,
                                                   uchar* __restrict__ pb,
                                                   float* __restrict__ sq) {
    int row = blockIdx.x;
    int t = threadIdx.x;
    const float4* prow = (const float4*)(p + (size_t)row * DIM);
    uint* qrow = (uint*)(pb + (size_t)row * DIM);
    float4 a = prow[t];          // elems 4t .. 4t+3
    float4 b = prow[t + 256];    // elems 1024+4t ..
    float s = a.x * a.x + a.y * a.y + a.z * a.z + a.w * a.w
            + b.x * b.x + b.y * b.y + b.z * b.z + b.w * b.w;
    qrow[t] = pack4(a);
    qrow[t + 256] = pack4(b);
#pragma unroll
    for (int o = 32; o > 0; o >>= 1) s += __shfl_down(s, o, 64);
    __shared__ float wsums[4];
    int lane = t & 63, wvv = t >> 6;
    if (lane == 0) wsums[wvv] = s;
    __syncthreads();
    if (t == 0) sq[row] = wsums[0] + wsums[1] + wsums[2] + wsums[3];
}

// ---------------- half-tile stage: global -> LDS (linear dest, pre-swizzled src)
// which: 0 = A half0, 1 = A half1, 2 = B half0, 3 = B half1, for K-tile t.
// t >= NKT clamps to t-2: same buffer/region (parity preserved), data dead.
__device__ __forceinline__ void stage_ht(const uchar* __restrict__ pb,
                                         uchar* lds, int t, int which,
                                         int ibase, int jbase, int tid) {
    if (t >= NKT) t -= 2;
    const int h = which & 1;
    const int row0 = ((which >= 2) ? jbase : ibase) + h * 128;
    const uchar* g0 = pb + (size_t)row0 * DIM + t * BKB;
    uchar* l0 = lds + (t & 1) * BUF_B + ((which >= 2) ? ABUF_B : 0) + h * HALF_B;
#pragma unroll
    for (int r = 0; r < 2; ++r) {
        int row = r * 64 + (tid >> 3);                 // row within half-tile
        int c8 = (tid & 7) ^ ((tid >> 3) & 7);         // pre-swizzled 16B slot
        const uchar* g = g0 + (size_t)row * DIM + c8 * 16;
        uchar* l = l0 + r * 8192 + (tid >> 6) * 1024;  // wave-uniform (+lane*16 HW)
        __builtin_amdgcn_global_load_lds(
            (const __attribute__((address_space(1))) uint32_t*)g,
            (__attribute__((address_space(3))) uint32_t*)l, 16, 0, 0);
    }
}

#define BARF()   do { __builtin_amdgcn_s_barrier(); \
                      asm volatile("" ::: "memory"); } while (0)
#define WAITL()  asm volatile("s_waitcnt lgkmcnt(0)" ::: "memory")
#define WAITV8() asm volatile("s_waitcnt vmcnt(8)" ::: "memory")
#define WAITV0() asm volatile("s_waitcnt vmcnt(0)" ::: "memory")
#define PRIO1()  __builtin_amdgcn_s_setprio(1)
#define PRIO0()  __builtin_amdgcn_s_setprio(0)

// swizzled ds_read of 16B i8 frags: row stride 128B, slot ^= (row&7) = (lane&7)
// A fragment: mtiles (MH)*2+mt (32 rows each), K-slices s=0..3 (K=32 each)
#define READ_A(AB, MH)                                                         \
    _Pragma("unroll") for (int mt = 0; mt < 2; ++mt)                           \
    _Pragma("unroll") for (int s = 0; s < 4; ++s) {                            \
        int rl = wr * 128 + ((MH) * 2 + mt) * 32 + (lane & 31);                \
        af[mt][s] = *(const int4v*)&(AB)[rl * 128 +                            \
                     (((2 * s + kh) ^ (lane & 7)) * 16)];                      \
    }

#define READ_B(BB, NH)                                                         \
    _Pragma("unroll") for (int s = 0; s < 4; ++s) {                            \
        int rl = wc * 64 + (NH) * 32 + (lane & 31);                            \
        bf[NH][s] = *(const int4v*)&(BB)[rl * 128 +                            \
                     (((2 * s + kh) ^ (lane & 7)) * 16)];                      \
    }

#define MFMA_Q(MH, NH)                                                         \
    _Pragma("unroll") for (int mt = 0; mt < 2; ++mt)                           \
    _Pragma("unroll") for (int s = 0; s < 4; ++s)                              \
        acc[(MH) * 2 + mt][NH] = __builtin_amdgcn_mfma_i32_32x32x32_i8(        \
            af[mt][s], bf[NH][s], acc[(MH) * 2 + mt][NH], 0, 0, 0);

// One K-tile = 4 phases. All stages for tile T+2 issue in P3/P4:
//   P3: B0,B1(T+2)->buf (safe: ALL B reads of buf close at end-P2 barrier)
//   P4: A0,A1(T+2)->buf (safe: ALL A reads of buf close at end-P3 barrier)
// Boundary s_waitcnt vmcnt(8): tile T+1's 8 loads retired, T+2's 8 in flight.
#define TILE_STEP(T, BUF)                                                      \
    {                                                                          \
        const uchar* Ab = &lds[(BUF) * BUF_B];                                 \
        const uchar* Bb = &lds[(BUF) * BUF_B + ABUF_B];                        \
        /* P1: Q(0,0) — 12 ds_reads, no stage */                               \
        READ_A(Ab, 0);                                                         \
        READ_B(Bb, 0);                                                         \
        BARF(); WAITL();                                                       \
        PRIO1(); MFMA_Q(0, 0); PRIO0();                                        \
        BARF();                                                                \
        /* P2: Q(0,1) — 4 ds_reads */                                          \
        READ_B(Bb, 1);                                                         \
        BARF(); WAITL();                                                       \
        PRIO1(); MFMA_Q(0, 1); PRIO0();                                        \
        BARF();                                                                \
        /* P3: Q(1,0) — 8 ds_reads + stage B(T+2) */                           \
        READ_A(Ab, 1);                                                         \
        stage_ht(pb, lds, (T) + 2, 2, ibase, jbase, tid);                      \
        stage_ht(pb, lds, (T) + 2, 3, ibase, jbase, tid);                      \
        BARF(); WAITL();                                                       \
        PRIO1(); MFMA_Q(1, 0); PRIO0();                                        \
        BARF();                                                                \
        /* P4: Q(1,1) — stage A(T+2), counted vmcnt at tile boundary */        \
        stage_ht(pb, lds, (T) + 2, 0, ibase, jbase, tid);                      \
        stage_ht(pb, lds, (T) + 2, 1, ibase, jbase, tid);                      \
        PRIO1(); MFMA_Q(1, 1); PRIO0();                                        \
        WAITV8();                                                              \
        BARF();                                                                \
    }

// ---------------- kernel 2: 256² i8 8-phase triangular Gram + fused loss ----
__global__ __launch_bounds__(512) void tile2_kernel(
    const uchar* __restrict__ pb, const float* __restrict__ sq,
    const int* __restrict__ gt, double* __restrict__ accum) {

    __shared__ uchar lds[2 * BUF_B];   // 128 KiB: 2 x (A[256][128] + B[256][128])
    __shared__ float wsum[8];

    int bid = (int)blockIdx.x;
    bid = (bid & 7) * 66 + (bid >> 3);   // bijective XCD swizzle (528 = 8*66)

    int ti, tj;
    decode_tile(bid, &ti, &tj);

    const int tid = threadIdx.x;
    const int lane = tid & 63;
    const int kh = lane >> 5;            // K-half within a 32-wide slice
    const int wv = tid >> 6;
    const int wr = wv >> 2;   // 0..1 : wave row (128 rows each)
    const int wc = wv & 3;    // 0..3 : wave col (64 cols each)
    const int ibase = ti * BT2;
    const int jbase = tj * BT2;

    int16v acc[4][2] = {};    // 4 Mtiles x 2 Ntiles of 32x32
    int4v af[2][4];
    int4v bf[2][4];

    // prologue: tiles 0,1 fully issued; vmcnt(8) -> tile 0 resident,
    // tile 1's 8 loads in flight (steady-state invariant).
    stage_ht(pb, lds, 0, 2, ibase, jbase, tid);
    stage_ht(pb, lds, 0, 3, ibase, jbase, tid);
    stage_ht(pb, lds, 0, 0, ibase, jbase, tid);
    stage_ht(pb, lds, 0, 1, ibase, jbase, tid);
    stage_ht(pb, lds, 1, 2, ibase, jbase, tid);
    stage_ht(pb, lds, 1, 3, ibase, jbase, tid);
    stage_ht(pb, lds, 1, 0, ibase, jbase, tid);
    stage_ht(pb, lds, 1, 1, ibase, jbase, tid);
    WAITV8();
    BARF();

#pragma unroll 1
    for (int s0 = 0; s0 < NKT; s0 += 2) {
        TILE_STEP(s0, 0);
        TILE_STEP(s0 + 1, 1);
    }
    WAITV0();   // drain dead tail stages before exit
    BARF();

    // fused epilogue: dequant -> d2 -> contrastive term -> weighted sum
    const float invd = 1.0f / (float)DIM;
    float lsum = 0.f;
    {
        int j0 = jbase + wc * 64 + (lane & 31);
        float sqj[2]; int gj[2];
#pragma unroll
        for (int n = 0; n < 2; ++n) { int j = j0 + n * 32; sqj[n] = sq[j]; gj[n] = gt[j]; }
        const float wb = (ti != tj) ? 2.0f : 1.0f;
#pragma unroll
        for (int mi = 0; mi < 4; ++mi) {
#pragma unroll
            for (int q = 0; q < 4; ++q) {
#pragma unroll
                for (int rr = 0; rr < 4; ++rr) {
                    // C/D: row = (reg&3) + 8*(reg>>2) + 4*(lane>>5), reg = q*4+rr
                    int i = ibase + wr * 128 + mi * 32 + rr + 8 * q + 4 * kh;
                    float sqi = sq[i];
                    int gi = gt[i];
#pragma unroll
                    for (int n = 0; n < 2; ++n) {
                        int j = j0 + n * 32;
                        float dot = S2 * (float)acc[mi][n][q * 4 + rr];
                        float d2 = fmaxf(sqi + sqj[n] - 2.0f * dot, 0.0f) * invd;
                        float term = (gi == gj[n]) ? d2 : fmaxf(MARGIN - d2, 0.0f);
                        float w = wb;
                        if (ti == tj && i == j) w = 2.0f;   // triu diagonal once*2
                        lsum += w * term;
                    }
                }
            }
        }
    }
#pragma unroll
    for (int o = 32; o > 0; o >>= 1) lsum += __shfl_down(lsum, o, 64);
    if (lane == 0) wsum[wv] = lsum;
    __syncthreads();
    if (tid == 0) {
        float s = 0.f;
#pragma unroll
        for (int w = 0; w < 8; ++w) s += wsum[w];
        atomicAdd(accum, (double)s);
    }
}

// ---------------- kernel 3: finalize ----------------------------------------
__global__ void finalize_kernel(const double* __restrict__ accum,
                                float* __restrict__ out) {
    if (threadIdx.x == 0)
        out[0] = (float)(accum[0] * (1.0 / ((double)NROWS * (double)(NROWS - 1))));
}

extern "C" void kernel_launch(void* const* d_in, const int* in_sizes, int n_in,
                              void* d_out, int out_size, void* d_ws, size_t ws_size,
                              hipStream_t stream) {
    (void)in_sizes; (void)n_in; (void)out_size; (void)ws_size;
    const float* p = (const float*)d_in[0];
    const int* gt = (const int*)d_in[1];
    float* out = (float*)d_out;

    // ws layout: pb 16MB i8 | sq 32KB | accum 8B
    uchar* pb = (uchar*)d_ws;
    size_t off = (size_t)NROWS * DIM;                   // 16,777,216
    float* sq = (float*)((char*)d_ws + off);
    off += (size_t)NROWS * sizeof(float);               // +32 KB
    double* accum = (double*)((char*)d_ws + off);

    (void)hipMemsetAsync(accum, 0, sizeof(double), stream);
    prep_kernel<<<NROWS, 256, 0, stream>>>(p, pb, sq);
    tile2_kernel<<<NTILES2, 512, 0, stream>>>(pb, sq, gt, accum);
    finalize_kernel<<<1, 64, 0, stream>>>(accum, out);
}

// Round 7
// 118.292 us; speedup vs baseline: 2.1243x; 1.0981x over previous
//
#include <hip/hip_runtime.h>
#include <stdint.h>

#define NROWS 8192
#define DIM   2048
#define MARGIN 2.0f
#define SCALEQ (127.0f / 6.0f)          // quantize scale
#define S2     ((6.0f / 127.0f) * (6.0f / 127.0f))   // dequant^2

// ---- 256x256 i8 tile kernel geometry (byte units) ----
#define BT2     256
#define BKB     128                      // K-bytes (=elems) per tile-step
#define NKT     (DIM / BKB)              // 16 K-tiles
#define NT2     (NROWS / BT2)            // 32 tile-rows
#define NTILES2 (NT2 * (NT2 + 1) / 2)    // 528 upper-tri tiles
#define NSPL    16                       // logical tiles 0..15 split into row-halves
#define ABUF_B  32768                    // A region bytes per buffer (256x128)
#define BUF_B   65536                    // A + B regions per buffer
#define HALF_B  16384                    // 128x128 half-tile bytes

typedef __attribute__((ext_vector_type(4)))  int  int4v;    // 4 VGPR operand
typedef __attribute__((ext_vector_type(16))) int  int16v;   // 32x32 i32 acc
typedef unsigned char uchar;

// triangular decode (ti <= tj): off(r) = r*NT2 - r(r-1)/2
__device__ __forceinline__ void decode_tile(int bid, int* ti, int* tj) {
    float fn = (float)NT2 + 0.5f;
    int r = (int)(fn - sqrtf(fn * fn - 2.0f * (float)bid));
    if (r < 0) r = 0;
    if (r >= NT2) r = NT2 - 1;
    while ((r + 1) * NT2 - ((r + 1) * r) / 2 <= bid) ++r;
    while (r * NT2 - (r * (r - 1)) / 2 > bid) --r;
    *ti = r;
    *tj = r + (bid - (r * NT2 - (r * (r - 1)) / 2));
}

__device__ __forceinline__ uint pack4(float4 v) {
    int q0 = (int)__builtin_rintf(v.x * SCALEQ);
    int q1 = (int)__builtin_rintf(v.y * SCALEQ);
    int q2 = (int)__builtin_rintf(v.z * SCALEQ);
    int q3 = (int)__builtin_rintf(v.w * SCALEQ);
    q0 = min(max(q0, -127), 127); q1 = min(max(q1, -127), 127);
    q2 = min(max(q2, -127), 127); q3 = min(max(q3, -127), 127);
    return (uint)(q0 & 0xFF) | ((uint)(q1 & 0xFF) << 8) |
           ((uint)(q2 & 0xFF) << 16) | ((uint)(q3 & 0xFF) << 24);
}

// ---------------- kernel 1: fp32 -> i8 quantize + fp32 row sum of squares ---
// sq from the fp32 ORIGINALS: cancels the quantization distance-inflation bias.
__global__ __launch_bounds__(256) void prep_kernel(const float* __restrict__ p,
                                                   uchar* __restrict__ pb,
                                                   float* __restrict__ sq) {
    int row = blockIdx.x;
    int t = threadIdx.x;
    const float4* prow = (const float4*)(p + (size_t)row * DIM);
    uint* qrow = (uint*)(pb + (size_t)row * DIM);
    float4 a = prow[t];
    float4 b = prow[t + 256];
    float s = a.x * a.x + a.y * a.y + a.z * a.z + a.w * a.w
            + b.x * b.x + b.y * b.y + b.z * b.z + b.w * b.w;
    qrow[t] = pack4(a);
    qrow[t + 256] = pack4(b);
#pragma unroll
    for (int o = 32; o > 0; o >>= 1) s += __shfl_down(s, o, 64);
    __shared__ float wsums[4];
    int lane = t & 63, wvv = t >> 6;
    if (lane == 0) wsums[wvv] = s;
    __syncthreads();
    if (t == 0) sq[row] = wsums[0] + wsums[1] + wsums[2] + wsums[3];
}

// ---------------- half-tile stage: global -> LDS (linear dest, pre-swizzled src)
// which: 0 = A half0, 1 = A half1, 2 = B half0, 3 = B half1, for K-tile t.
// t >= NKT clamps to t-2: same buffer/region (parity preserved), data dead.
__device__ __forceinline__ void stage_ht(const uchar* __restrict__ pb,
                                         uchar* lds, int t, int which,
                                         int ibase, int jbase, int tid) {
    if (t >= NKT) t -= 2;
    const int h = which & 1;
    const int row0 = ((which >= 2) ? jbase : ibase) + h * 128;
    const uchar* g0 = pb + (size_t)row0 * DIM + t * BKB;
    uchar* l0 = lds + (t & 1) * BUF_B + ((which >= 2) ? ABUF_B : 0) + h * HALF_B;
#pragma unroll
    for (int r = 0; r < 2; ++r) {
        int row = r * 64 + (tid >> 3);                 // row within half-tile
        int c8 = (tid & 7) ^ ((tid >> 3) & 7);         // pre-swizzled 16B slot
        const uchar* g = g0 + (size_t)row * DIM + c8 * 16;
        uchar* l = l0 + r * 8192 + (tid >> 6) * 1024;  // wave-uniform (+lane*16 HW)
        __builtin_amdgcn_global_load_lds(
            (const __attribute__((address_space(1))) uint32_t*)g,
            (__attribute__((address_space(3))) uint32_t*)l, 16, 0, 0);
    }
}

#define BARF()   do { __builtin_amdgcn_s_barrier(); \
                      asm volatile("" ::: "memory"); } while (0)
#define WAITL()  asm volatile("s_waitcnt lgkmcnt(0)" ::: "memory")
#define WAITV8() asm volatile("s_waitcnt vmcnt(8)" ::: "memory")
#define WAITV6() asm volatile("s_waitcnt vmcnt(6)" ::: "memory")
#define WAITV0() asm volatile("s_waitcnt vmcnt(0)" ::: "memory")
#define PRIO1()  __builtin_amdgcn_s_setprio(1)
#define PRIO0()  __builtin_amdgcn_s_setprio(0)

// swizzled ds_read of 16B i8 frags: row stride 128B, slot ^= (row&7) = (lane&7)
#define READ_A(AB, MH)                                                         \
    _Pragma("unroll") for (int mt = 0; mt < 2; ++mt)                           \
    _Pragma("unroll") for (int s = 0; s < 4; ++s) {                            \
        int rl = wr * 128 + ((MH) * 2 + mt) * 32 + (lane & 31);                \
        af[mt][s] = *(const int4v*)&(AB)[rl * 128 +                            \
                     (((2 * s + kh) ^ (lane & 7)) * 16)];                      \
    }

#define READ_B(BB, NH)                                                         \
    _Pragma("unroll") for (int s = 0; s < 4; ++s) {                            \
        int rl = wc * 64 + (NH) * 32 + (lane & 31);                            \
        bf[NH][s] = *(const int4v*)&(BB)[rl * 128 +                            \
                     (((2 * s + kh) ^ (lane & 7)) * 16)];                      \
    }

#define MFMA_Q(MH, NH)                                                         \
    _Pragma("unroll") for (int mt = 0; mt < 2; ++mt)                           \
    _Pragma("unroll") for (int s = 0; s < 4; ++s)                              \
        acc[(MH) * 2 + mt][NH] = __builtin_amdgcn_mfma_i32_32x32x32_i8(        \
            af[mt][s], bf[NH][s], acc[(MH) * 2 + mt][NH], 0, 0, 0);

// FULL step: 2 barriers. Reads of buf(T) all complete before mid-barrier;
// stages (T+2 -> buf(T)) issue after it; Q(1,*) MFMAs cover the stage issues;
// WAITV8 at end: T+1's 8 loads retired, T+2's 8 in flight. Compiler inserts
// counted lgkmcnt for the MFMA operand deps (reads flow under Q(0,*) MFMAs).
#define STEP_FULL(T, BUF)                                                      \
    {                                                                          \
        const uchar* Ab = &lds[(BUF) * BUF_B];                                 \
        const uchar* Bb = &lds[(BUF) * BUF_B + ABUF_B];                        \
        READ_A(Ab, 0);                                                         \
        READ_B(Bb, 0);                                                         \
        READ_B(Bb, 1);                                                         \
        PRIO1(); MFMA_Q(0, 0); MFMA_Q(0, 1); PRIO0();                          \
        READ_A(Ab, 1);                                                         \
        WAITL(); BARF();                                                       \
        stage_ht(pb, lds, (T) + 2, 2, ibase, jbase, tid);                      \
        stage_ht(pb, lds, (T) + 2, 3, ibase, jbase, tid);                      \
        stage_ht(pb, lds, (T) + 2, 0, ibase, jbase, tid);                      \
        stage_ht(pb, lds, (T) + 2, 1, ibase, jbase, tid);                      \
        PRIO1(); MFMA_Q(1, 0); MFMA_Q(1, 1); PRIO0();                          \
        WAITV8(); BARF();                                                      \
    }

// HALF (128x256 row-half) step: A = which0 only (128 rows), 6 issues/step.
#define STEP_HALF(T, BUF)                                                      \
    {                                                                          \
        const uchar* Ab = &lds[(BUF) * BUF_B];                                 \
        const uchar* Bb = &lds[(BUF) * BUF_B + ABUF_B];                        \
        _Pragma("unroll") for (int mt = 0; mt < 2; ++mt)                       \
        _Pragma("unroll") for (int s = 0; s < 4; ++s) {                        \
            int rl = wrh * 64 + mt * 32 + (lane & 31);                         \
            af[mt][s] = *(const int4v*)&Ab[rl * 128 +                          \
                         (((2 * s + kh) ^ (lane & 7)) * 16)];                  \
        }                                                                      \
        READ_B(Bb, 0);                                                         \
        READ_B(Bb, 1);                                                         \
        PRIO1();                                                               \
        _Pragma("unroll") for (int mt = 0; mt < 2; ++mt)                       \
        _Pragma("unroll") for (int s = 0; s < 4; ++s)                          \
            acc[mt][0] = __builtin_amdgcn_mfma_i32_32x32x32_i8(                \
                af[mt][s], bf[0][s], acc[mt][0], 0, 0, 0);                     \
        _Pragma("unroll") for (int mt = 0; mt < 2; ++mt)                       \
        _Pragma("unroll") for (int s = 0; s < 4; ++s)                          \
            acc[mt][1] = __builtin_amdgcn_mfma_i32_32x32x32_i8(                \
                af[mt][s], bf[1][s], acc[mt][1], 0, 0, 0);                     \
        PRIO0();                                                               \
        WAITL(); BARF();                                                       \
        stage_ht(pb, lds, (T) + 2, 0, ibase, jbase, tid);                      \
        stage_ht(pb, lds, (T) + 2, 2, ibase, jbase, tid);                      \
        stage_ht(pb, lds, (T) + 2, 3, ibase, jbase, tid);                      \
        WAITV6(); BARF();                                                      \
    }

// ---------------- kernel 2: triangular Gram + fused loss --------------------
// Grid = 32 row-halves (tiles 0..15, dispatched first) + 512 full tiles.
__global__ __launch_bounds__(512) void tile2_kernel(
    const uchar* __restrict__ pb, const float* __restrict__ sq,
    const int* __restrict__ gt, double* __restrict__ accum) {

    __shared__ uchar lds[2 * BUF_B];   // 128 KiB
    __shared__ float wsum[8];

    const int bx = (int)blockIdx.x;
    const bool is_half = (bx < 2 * NSPL);
    int bid, hh = 0;
    if (is_half) { bid = bx >> 1; hh = bx & 1; }
    else { int f = bx - 2 * NSPL; bid = NSPL + ((f & 7) << 6) + (f >> 3); } // 512=8*64

    int ti, tj;
    decode_tile(bid, &ti, &tj);

    const int tid = threadIdx.x;
    const int lane = tid & 63;
    const int kh = lane >> 5;            // K-half within a 32-wide slice
    const int wv = tid >> 6;
    const int wc = wv & 3;               // 0..3 : wave col (64 cols each)
    const int jbase = tj * BT2;
    const int ibase = ti * BT2 + (is_half ? hh * 128 : 0);

    const float invd = 1.0f / (float)DIM;
    float lsum = 0.f;

    if (!is_half) {
        const int wr = wv >> 2;          // 0..1 : wave row (128 rows each)
        int16v acc[4][2] = {};
        int4v af[2][4];
        int4v bf[2][4];

        // prologue: tiles 0,1 fully issued; vmcnt(8) -> tile0 resident.
        stage_ht(pb, lds, 0, 2, ibase, jbase, tid);
        stage_ht(pb, lds, 0, 3, ibase, jbase, tid);
        stage_ht(pb, lds, 0, 0, ibase, jbase, tid);
        stage_ht(pb, lds, 0, 1, ibase, jbase, tid);
        stage_ht(pb, lds, 1, 2, ibase, jbase, tid);
        stage_ht(pb, lds, 1, 3, ibase, jbase, tid);
        stage_ht(pb, lds, 1, 0, ibase, jbase, tid);
        stage_ht(pb, lds, 1, 1, ibase, jbase, tid);
        WAITV8();
        BARF();

#pragma unroll 1
        for (int s0 = 0; s0 < NKT; s0 += 2) {
            STEP_FULL(s0, 0);
            STEP_FULL(s0 + 1, 1);
        }
        WAITV0();
        BARF();

        // fused epilogue: dequant -> d2 -> contrastive term -> weighted sum
        int j0 = jbase + wc * 64 + (lane & 31);
        float sqj[2]; int gj[2];
#pragma unroll
        for (int n = 0; n < 2; ++n) { int j = j0 + n * 32; sqj[n] = sq[j]; gj[n] = gt[j]; }
        const float wb = (ti != tj) ? 2.0f : 1.0f;
#pragma unroll
        for (int mi = 0; mi < 4; ++mi) {
#pragma unroll
            for (int q = 0; q < 4; ++q) {
#pragma unroll
                for (int rr = 0; rr < 4; ++rr) {
                    int i = ibase + wr * 128 + mi * 32 + rr + 8 * q + 4 * kh;
                    float sqi = sq[i];
                    int gi = gt[i];
#pragma unroll
                    for (int n = 0; n < 2; ++n) {
                        int j = j0 + n * 32;
                        float dot = S2 * (float)acc[mi][n][q * 4 + rr];
                        float d2 = fmaxf(sqi + sqj[n] - 2.0f * dot, 0.0f) * invd;
                        float term = (gi == gj[n]) ? d2 : fmaxf(MARGIN - d2, 0.0f);
                        float w = wb;
                        if (ti == tj && i == j) w = 2.0f;
                        lsum += w * term;
                    }
                }
            }
        }
    } else {
        const int wrh = wv >> 2;         // 0..1 : wave row (64 rows each)
        int16v acc[2][2] = {};
        int4v af[2][4];
        int4v bf[2][4];

        // prologue: tiles 0,1 {A0,B0,B1}; vmcnt(6) -> tile0 resident.
        stage_ht(pb, lds, 0, 0, ibase, jbase, tid);
        stage_ht(pb, lds, 0, 2, ibase, jbase, tid);
        stage_ht(pb, lds, 0, 3, ibase, jbase, tid);
        stage_ht(pb, lds, 1, 0, ibase, jbase, tid);
        stage_ht(pb, lds, 1, 2, ibase, jbase, tid);
        stage_ht(pb, lds, 1, 3, ibase, jbase, tid);
        WAITV6();
        BARF();

#pragma unroll 1
        for (int s0 = 0; s0 < NKT; s0 += 2) {
            STEP_HALF(s0, 0);
            STEP_HALF(s0 + 1, 1);
        }
        WAITV0();
        BARF();

        int j0 = jbase + wc * 64 + (lane & 31);
        float sqj[2]; int gj[2];
#pragma unroll
        for (int n = 0; n < 2; ++n) { int j = j0 + n * 32; sqj[n] = sq[j]; gj[n] = gt[j]; }
        const float wb = (ti != tj) ? 2.0f : 1.0f;
#pragma unroll
        for (int mt = 0; mt < 2; ++mt) {
#pragma unroll
            for (int q = 0; q < 4; ++q) {
#pragma unroll
                for (int rr = 0; rr < 4; ++rr) {
                    int i = ibase + wrh * 64 + mt * 32 + rr + 8 * q + 4 * kh;
                    float sqi = sq[i];
                    int gi = gt[i];
#pragma unroll
                    for (int n = 0; n < 2; ++n) {
                        int j = j0 + n * 32;
                        float dot = S2 * (float)acc[mt][n][q * 4 + rr];
                        float d2 = fmaxf(sqi + sqj[n] - 2.0f * dot, 0.0f) * invd;
                        float term = (gi == gj[n]) ? d2 : fmaxf(MARGIN - d2, 0.0f);
                        float w = wb;
                        if (ti == tj && i == j) w = 2.0f;
                        lsum += w * term;
                    }
                }
            }
        }
    }

#pragma unroll
    for (int o = 32; o > 0; o >>= 1) lsum += __shfl_down(lsum, o, 64);
    if (lane == 0) wsum[wv] = lsum;
    __syncthreads();
    if (tid == 0) {
        float s = 0.f;
#pragma unroll
        for (int w = 0; w < 8; ++w) s += wsum[w];
        atomicAdd(accum, (double)s);
    }
}

// ---------------- kernel 3: finalize ----------------------------------------
__global__ void finalize_kernel(const double* __restrict__ accum,
                                float* __restrict__ out) {
    if (threadIdx.x == 0)
        out[0] = (float)(accum[0] * (1.0 / ((double)NROWS * (double)(NROWS - 1))));
}

extern "C" void kernel_launch(void* const* d_in, const int* in_sizes, int n_in,
                              void* d_out, int out_size, void* d_ws, size_t ws_size,
                              hipStream_t stream) {
    (void)in_sizes; (void)n_in; (void)out_size; (void)ws_size;
    const float* p = (const float*)d_in[0];
    const int* gt = (const int*)d_in[1];
    float* out = (float*)d_out;

    // ws layout: pb 16MB i8 | sq 32KB | accum 8B
    uchar* pb = (uchar*)d_ws;
    size_t off = (size_t)NROWS * DIM;                   // 16,777,216
    float* sq = (float*)((char*)d_ws + off);
    off += (size_t)NROWS * sizeof(float);               // +32 KB
    double* accum = (double*)((char*)d_ws + off);

    (void)hipMemsetAsync(accum, 0, sizeof(double), stream);
    prep_kernel<<<NROWS, 256, 0, stream>>>(p, pb, sq);
    tile2_kernel<<<2 * NSPL + 512, 512, 0, stream>>>(pb, sq, gt, accum);
    finalize_kernel<<<1, 64, 0, stream>>>(accum, out);
}